// Round 9
// baseline (450.483 us; speedup 1.0000x reference)
//
#include <hip/hip_runtime.h>

#define N_NODES 100000
#define N_EDGES 50000
#define NNZ_    400000
#define MP 100032   // N_NODES padded to 64
#define EP 50048    // N_EDGES padded to 64
#define NBLK_N 1563 // ceil(100000/64)  blocks per node-agg panel
#define NBLK_E 391  // ceil(50000/128)  blocks per edge-agg panel

typedef unsigned short ushort_t;
typedef unsigned int uint_t;

typedef __attribute__((ext_vector_type(8))) short bf16x8;
typedef __attribute__((ext_vector_type(4))) float f32x4;

__device__ __forceinline__ float b2f(ushort_t u) {
    return __uint_as_float(((uint_t)u) << 16);
}
__device__ __forceinline__ ushort_t f2b(float f) {
    uint_t x = __float_as_uint(f);
    uint_t r = (x + 0x7fffu + ((x >> 16) & 1u)) >> 16;  // RNE
    return (ushort_t)r;
}
__device__ __forceinline__ float ldval(const void* p, int k, int bf) {
    return bf ? b2f(((const ushort_t*)p)[k]) : ((const float*)p)[k];
}
__device__ __forceinline__ float vb(bf16x8 v, int j) {
    return __uint_as_float(((uint_t)(ushort_t)v[j]) << 16);
}

__global__ void k_sentinel(void* out) { ((uint_t*)out)[0] = 0x44894489u; }

__global__ void k_zero(uint_t* p, size_t n) {
    size_t i = (size_t)blockIdx.x * 256 + threadIdx.x;
    size_t stride = (size_t)gridDim.x * 256;
    for (; i < n; i += stride) p[i] = 0u;
}

// flags[0]=dtype(1=bf16), flags[2]=edge-structure violation, flags[3]=node-deg!=4
// fused: structure checks + fast node-CSR fill (stores EDGE id k>>3 per slot)
__global__ void k_checkfill(const void* __restrict__ vals, const int* __restrict__ rows,
                            const int* __restrict__ cols, int* ncntA, int* nidx,
                            int* flags) {
    int k = blockIdx.x * 256 + threadIdx.x;
    int bf = (((const uint_t*)vals)[0] == 0x3F803F80u);
    if (k == 0 && blockIdx.x == 0) flags[0] = bf;
    if (k >= NNZ_) return;
    int bad = 0;
    if (cols[k] != (k >> 3)) bad = 1;
    if (bf) { if (((const ushort_t*)vals)[k] != 0x3F80) bad = 1; }
    else    { if (((const uint_t*)vals)[k] != 0x3F800000u) bad = 1; }
    if (bad) atomicOr(&flags[2], 1);
    int r = rows[k];
    if ((unsigned)r >= (unsigned)N_NODES) { atomicOr(&flags[3], 1); return; }
    int slot = atomicAdd(&ncntA[r], 1);
    if (slot < 4) nidx[r * 4 + slot] = (k >> 3);   // edge id directly
    else atomicOr(&flags[3], 1);
}

// conversions fused: x0 -> bf16 (skipped when already bf16), weights -> transposed bf16,
// smalls -> f32
__global__ void k_cvt_all(const void* x0, const void* W0l0, const void* W1l0,
                          const void* W0l1, const void* W1l1,
                          const void* b1l0, const void* b0l0, const void* b1l1,
                          const void* b0l1, const void* lw, const void* lb,
                          ushort_t* x0c, ushort_t* Wt0_l0, ushort_t* Wt1_l0,
                          ushort_t* Wt0_l1, ushort_t* Wt1_l1,
                          float* smallf, const int* __restrict__ flags) {
    int bf = flags[0];
    long i = (long)blockIdx.x * 256 + threadIdx.x;
    const long R0V = (long)N_NODES * 64 / 8;   // 800000 vector items
    if (i < R0V) {
        if (!bf) {   // bf16 inputs used in place; only f32 needs conversion
            const float* s = (const float*)x0 + i * 8;
            bf16x8 o;
#pragma unroll
            for (int j = 0; j < 8; ++j) o[j] = (short)f2b(s[j]);
            *(bf16x8*)(x0c + i * 8) = o;
        }
        return;
    }
    i -= R0V;
    if (i < 64 * 256) {
        int kk = i >> 8, n = i & 255;
        Wt0_l0[n * 64 + kk] = bf ? ((const ushort_t*)W0l0)[i] : f2b(((const float*)W0l0)[i]);
        return;
    }
    i -= 64 * 256;
    if (i < 65536) {
        int kk = i >> 8, n = i & 255;
        Wt1_l0[n * 256 + kk] = bf ? ((const ushort_t*)W1l0)[i] : f2b(((const float*)W1l0)[i]);
        return;
    }
    i -= 65536;
    if (i < 65536) {
        int kk = i >> 8, n = i & 255;
        Wt0_l1[n * 256 + kk] = bf ? ((const ushort_t*)W0l1)[i] : f2b(((const float*)W0l1)[i]);
        return;
    }
    i -= 65536;
    if (i < 65536) {
        int kk = i >> 8, n = i & 255;
        Wt1_l1[n * 256 + kk] = bf ? ((const ushort_t*)W1l1)[i] : f2b(((const float*)W1l1)[i]);
        return;
    }
    i -= 65536;
    if (i < 1536) {
        int b = i >> 8, t = i & 255;
        const void* srcs[6] = {b1l0, b0l0, b1l1, b0l1, lw, lb};
        int sz = (b == 5) ? 1 : 256;
        if (t < sz) smallf[b * 256 + t] = ldval(srcs[b], t, bf);
    }
}

// ---- general-path fallback: everything in ONE single-block kernel (early-exits fast) ----
__global__ __launch_bounds__(1024) void k_genprep(
        const void* __restrict__ vals, const int* __restrict__ rows,
        const int* __restrict__ cols, int* ncnt, int* ecnt,
        float* ndelta, float* edelta, float* ncard, float* ecard,
        float* d0, float* d1, int* nptr, int* eptr, int* nidx, int* eidx,
        int2* pairN, int2* pairE, const int* __restrict__ flags) {
    if ((flags[2] | flags[3]) == 0) return;
    __shared__ int ss[1024];
    int t = threadIdx.x;
    int bf = flags[0];
    for (int i = t; i < MP; i += 1024) { ncnt[i] = 0; ndelta[i] = 0.f; d0[i] = 0.f; }
    for (int i = t; i < EP; i += 1024) { ecnt[i] = 0; edelta[i] = 0.f; d1[i] = 0.f; }
    __syncthreads();
    for (int k = t; k < NNZ_; k += 1024) {
        int r = rows[k], c = cols[k];
        if ((unsigned)r < (unsigned)N_NODES) atomicAdd(&ncnt[r], 1);
        if ((unsigned)c < (unsigned)N_EDGES) atomicAdd(&ecnt[c], 1);
        float v = ldval(vals, k, bf);
        if (v != 1.0f && (unsigned)r < (unsigned)N_NODES && (unsigned)c < (unsigned)N_EDGES) {
            atomicAdd(&ndelta[r], v - 1.f); atomicAdd(&edelta[c], v - 1.f);
        }
    }
    __syncthreads();
    for (int i = t; i < N_NODES; i += 1024) ncard[i] = rsqrtf((float)ncnt[i] + ndelta[i]);
    for (int i = t; i < N_EDGES; i += 1024) {
        float s = (float)ecnt[i] + edelta[i];
        ecard[i] = 1.f / (s * sqrtf(s));
    }
    __syncthreads();
    for (int k = t; k < NNZ_; k += 1024) {
        int r = rows[k], c = cols[k];
        if ((unsigned)r >= (unsigned)N_NODES || (unsigned)c >= (unsigned)N_EDGES) continue;
        float v = ldval(vals, k, bf);
        if (v != 0.f) {
            atomicAdd(&d0[r], ecard[c]); atomicAdd(&d1[c], ncard[r]);
        }
    }
    __syncthreads();
    {
        int chunk = (N_NODES + 1023) / 1024;
        int lo = t * chunk, hi = min(lo + chunk, N_NODES);
        int s = 0;
        for (int i = lo; i < hi; ++i) s += ncnt[i];
        ss[t] = s; __syncthreads();
        if (t == 0) {
            int acc = 0;
            for (int i = 0; i < 1024; ++i) { int x = ss[i]; ss[i] = acc; acc += x; }
            nptr[N_NODES] = acc;
        }
        __syncthreads();
        int acc = ss[t];
        for (int i = lo; i < hi; ++i) { nptr[i] = acc; acc += ncnt[i]; }
        __syncthreads();
        chunk = (N_EDGES + 1023) / 1024;
        lo = t * chunk; hi = min(lo + chunk, N_EDGES);
        s = 0;
        for (int i = lo; i < hi; ++i) s += ecnt[i];
        ss[t] = s; __syncthreads();
        if (t == 0) {
            int acc2 = 0;
            for (int i = 0; i < 1024; ++i) { int x = ss[i]; ss[i] = acc2; acc2 += x; }
            eptr[N_EDGES] = acc2;
        }
        __syncthreads();
        acc = ss[t];
        for (int i = lo; i < hi; ++i) { eptr[i] = acc; acc += ecnt[i]; }
        __syncthreads();
    }
    for (int i = t; i < N_NODES; i += 1024) ncnt[i] = 0;
    for (int i = t; i < N_EDGES; i += 1024) ecnt[i] = 0;
    __syncthreads();
    for (int k = t; k < NNZ_; k += 1024) {
        int r = rows[k], c = cols[k];
        if ((unsigned)r >= (unsigned)N_NODES || (unsigned)c >= (unsigned)N_EDGES) continue;
        nidx[nptr[r] + atomicAdd(&ncnt[r], 1)] = k;
        eidx[eptr[c] + atomicAdd(&ecnt[c], 1)] = k;
    }
    __syncthreads();
    int tot = nptr[N_NODES];
    for (int i = t; i < tot; i += 1024) {
        int k = nidx[i];
        int r = rows[k], c = cols[k];
        float wn = ldval(vals, k, bf) * ecard[c] / d0[r];
        pairN[i] = make_int2(c, __float_as_int(wn));
    }
    int tote = eptr[N_EDGES];
    for (int i = t; i < tote; i += 1024) {
        int ke = eidx[i];
        int rr = rows[ke];
        float wt = ldval(vals, ke, bf) * ncard[rr] / d1[cols[ke]];
        pairE[i] = make_int2(rr, __float_as_int(wt));
    }
}

// ---------------- GEMM: C[M,256] = A[M,K] @ W (Wt [256][K] transposed) ----------------
template <int K>
__global__ __launch_bounds__(256) void k_gemm2(const ushort_t* __restrict__ A,
                                               const ushort_t* __restrict__ Wt,
                                               ushort_t* __restrict__ C,
                                               const float* __restrict__ bias,
                                               int do_relu) {
    __shared__ ushort_t lds[32 * 512];   // 32 frags x 512 ushorts = 32 KB
    const int tid = threadIdx.x;
    const int lane = tid & 63;
    const int wave = tid >> 6;
    const int r16 = lane & 15;
    const int quad = lane >> 4;
    const int nh = blockIdx.x & 1;
    const int mblk = blockIdx.x >> 1;
    const int nbase = nh * 128;
    const int mbase = mblk * 64 + wave * 16;
    const ushort_t* Arow = A + (size_t)(mbase + r16) * K;

    f32x4 acc[8];
#pragma unroll
    for (int t = 0; t < 8; ++t) acc[t] = (f32x4){0.f, 0.f, 0.f, 0.f};

    constexpr int KCH = (K < 128) ? K : 128;
    constexpr int NF = (KCH / 32) * 8;
    for (int kc = 0; kc < K; kc += KCH) {
        __syncthreads();
        for (int f = wave; f < NF; f += 4) {
            int kb = f >> 3, t = f & 7;
            int n = nbase + t * 16 + r16;
            int kg = kc + kb * 32 + quad * 8;
            *(bf16x8*)(&lds[f * 512 + lane * 8]) = *(const bf16x8*)(Wt + (size_t)n * K + kg);
        }
        __syncthreads();
#pragma unroll
        for (int k0 = 0; k0 < KCH; k0 += 32) {
            bf16x8 af = *(const bf16x8*)(Arow + kc + k0 + quad * 8);
#pragma unroll
            for (int t = 0; t < 8; ++t) {
                bf16x8 bfr = *(const bf16x8*)(&lds[((k0 >> 5) * 8 + t) * 512 + lane * 8]);
                acc[t] = __builtin_amdgcn_mfma_f32_16x16x32_bf16(af, bfr, acc[t], 0, 0, 0);
            }
        }
    }
    const int mo = mbase + quad * 4;
#pragma unroll
    for (int t = 0; t < 8; ++t) {
        int n = nbase + t * 16 + r16;
        float b = bias ? bias[n] : 0.f;
#pragma unroll
        for (int r = 0; r < 4; ++r) {
            float v = acc[t][r] + b;
            if (do_relu) v = fmaxf(v, 0.f);
            C[(size_t)(mo + r) * 256 + n] = f2b(v);
        }
    }
}

// ---- edge agg, channel-panel: dst[e][panel] = (1/8) * sum src[rows[8e+j]][panel] ----
// grid panel-major: concurrently-active blocks share one <=3.2MB source slice (L2-resident)
template <int C>
__global__ __launch_bounds__(256) void k_aggEp(const ushort_t* __restrict__ srcA,
                                               const ushort_t* __restrict__ srcB,
                                               const int* __restrict__ rows,
                                               const int* __restrict__ eptr,
                                               const int2* __restrict__ pairE,
                                               ushort_t* __restrict__ dst,
                                               const int* __restrict__ flags) {
    const int panel = blockIdx.x / NBLK_E;
    const int blk = blockIdx.x % NBLK_E;
    const int sub = threadIdx.x >> 1;        // 0..127 segment in block
    const int ch = panel * 16 + (threadIdx.x & 1) * 8;
    const int seg = blk * 128 + sub;
    if (seg >= N_EDGES) return;              // no barrier below: safe early exit
    const ushort_t* src = flags[0] ? srcA : srcB;
    float acc[8];
    if ((flags[2] | flags[3]) == 0) {
        int4 a0 = *(const int4*)(rows + seg * 8);
        int4 a1 = *(const int4*)(rows + seg * 8 + 4);
        bf16x8 v0 = *(const bf16x8*)(src + (size_t)a0.x * C + ch);
        bf16x8 v1 = *(const bf16x8*)(src + (size_t)a0.y * C + ch);
        bf16x8 v2 = *(const bf16x8*)(src + (size_t)a0.z * C + ch);
        bf16x8 v3 = *(const bf16x8*)(src + (size_t)a0.w * C + ch);
        bf16x8 v4 = *(const bf16x8*)(src + (size_t)a1.x * C + ch);
        bf16x8 v5 = *(const bf16x8*)(src + (size_t)a1.y * C + ch);
        bf16x8 v6 = *(const bf16x8*)(src + (size_t)a1.z * C + ch);
        bf16x8 v7 = *(const bf16x8*)(src + (size_t)a1.w * C + ch);
#pragma unroll
        for (int j = 0; j < 8; ++j)
            acc[j] = 0.125f * (((vb(v0,j) + vb(v1,j)) + (vb(v2,j) + vb(v3,j))) +
                               ((vb(v4,j) + vb(v5,j)) + (vb(v6,j) + vb(v7,j))));
    } else {
#pragma unroll
        for (int j = 0; j < 8; ++j) acc[j] = 0.f;
        int lo = eptr[seg], hi = eptr[seg + 1];
        for (int i = lo; i < hi; ++i) {
            int2 pr = pairE[i];
            float w = __int_as_float(pr.y);
            bf16x8 v = *(const bf16x8*)(src + (size_t)pr.x * C + ch);
#pragma unroll
            for (int j = 0; j < 8; ++j) acc[j] += w * vb(v, j);
        }
    }
    bf16x8 o;
#pragma unroll
    for (int j = 0; j < 8; ++j) o[j] = (short)f2b(acc[j]);
    *(bf16x8*)(dst + (size_t)seg * C + ch) = o;
}

// ---- node agg, channel-panel: dst[v] = relu(bias + 0.25 * sum src[edge]); POOL fuses max ----
template <int POOL>
__global__ __launch_bounds__(256) void k_aggNp(const ushort_t* __restrict__ src,
                                               const int* __restrict__ nidx,
                                               const int* __restrict__ nptr,
                                               const int2* __restrict__ pairN,
                                               const float* __restrict__ bias,
                                               ushort_t* __restrict__ dst,
                                               float* __restrict__ partial,
                                               const int* __restrict__ flags) {
    __shared__ float sm[64][33];
    const int panel = blockIdx.x / NBLK_N;
    const int blk = blockIdx.x % NBLK_N;
    const int sub = threadIdx.x >> 2;        // 0..63 segment in block
    const int chp = (threadIdx.x & 3) * 8;   // channel within 32-ch panel
    const int ch = panel * 32 + chp;
    const int seg = blk * 64 + sub;
    const int valid = (seg < N_NODES);
    if (!POOL && !valid) return;             // POOL path needs all threads for the barrier
    float acc[8];
    if (valid) {
        if ((flags[2] | flags[3]) == 0) {
            int4 i4 = *(const int4*)(nidx + seg * 4);   // edge ids
            bf16x8 v0 = *(const bf16x8*)(src + (size_t)i4.x * 256 + ch);
            bf16x8 v1 = *(const bf16x8*)(src + (size_t)i4.y * 256 + ch);
            bf16x8 v2 = *(const bf16x8*)(src + (size_t)i4.z * 256 + ch);
            bf16x8 v3 = *(const bf16x8*)(src + (size_t)i4.w * 256 + ch);
#pragma unroll
            for (int j = 0; j < 8; ++j)
                acc[j] = 0.25f * ((vb(v0,j) + vb(v1,j)) + (vb(v2,j) + vb(v3,j)));
        } else {
#pragma unroll
            for (int j = 0; j < 8; ++j) acc[j] = 0.f;
            int lo = nptr[seg], hi = nptr[seg + 1];
            for (int i = lo; i < hi; ++i) {
                int2 pr = pairN[i];
                float w = __int_as_float(pr.y);
                bf16x8 v = *(const bf16x8*)(src + (size_t)pr.x * 256 + ch);
#pragma unroll
                for (int j = 0; j < 8; ++j) acc[j] += w * vb(v, j);
            }
        }
    } else {
#pragma unroll
        for (int j = 0; j < 8; ++j) acc[j] = 0.f;   // neutral for max (post-ReLU >= 0)
    }
    if (POOL) {
#pragma unroll
        for (int j = 0; j < 8; ++j)
            sm[sub][chp + j] = valid ? fmaxf(acc[j] + bias[ch + j], 0.f) : 0.f;
        __syncthreads();
        if (threadIdx.x < 32) {
            float m = sm[0][threadIdx.x];
#pragma unroll 8
            for (int g = 1; g < 64; ++g) m = fmaxf(m, sm[g][threadIdx.x]);
            partial[(size_t)blockIdx.x * 32 + threadIdx.x] = m;
        }
    } else {
        bf16x8 o;
#pragma unroll
        for (int j = 0; j < 8; ++j)
            o[j] = (short)f2b(fmaxf(acc[j] + bias[ch + j], 0.f));
        *(bf16x8*)(dst + (size_t)seg * 256 + ch) = o;
    }
}

// ---------------- pool partial reduce + head ----------------
__global__ void k_pred(const float* __restrict__ partial, float* pooled) {
    int ch = threadIdx.x;
    int panel = ch >> 5, i = ch & 31;
    float m = 0.f;   // post-ReLU >= 0
    for (int b = blockIdx.x; b < NBLK_N; b += gridDim.x)
        m = fmaxf(m, partial[(size_t)(panel * NBLK_N + b) * 32 + i]);
    atomicMax((int*)&pooled[ch], __float_as_int(m));
}

__global__ void k_final(const float* __restrict__ pooled, const float* __restrict__ smallf,
                        void* out, const int* __restrict__ flags) {
    __shared__ float red[256];
    int c = threadIdx.x;
    red[c] = pooled[c] * smallf[4 * 256 + c];   // lin_w
    __syncthreads();
    for (int s = 128; s > 0; s >>= 1) {
        if (c < s) red[c] += red[c + s];
        __syncthreads();
    }
    if (c == 0) {
        float r = red[0] + smallf[5 * 256 + 0]; // lin_b
        if (flags[0]) ((ushort_t*)out)[0] = f2b(r);
        else          ((float*)out)[0] = r;
    }
}

extern "C" void kernel_launch(void* const* d_in, const int* in_sizes, int n_in,
                              void* d_out, int out_size, void* d_ws, size_t ws_size,
                              hipStream_t stream) {
    const void* x0_in = d_in[0];
    const void* vals  = d_in[1];
    const int* rows = (const int*)d_in[2];
    const int* cols = (const int*)d_in[3];
    const void* W0_l0 = d_in[4];
    const void* W1_l0 = d_in[5];
    const void* b1_l0 = d_in[6];
    const void* b0_l0 = d_in[7];
    const void* W0_l1 = d_in[8];
    const void* W1_l1 = d_in[9];
    const void* b1_l1 = d_in[10];
    const void* b0_l1 = d_in[11];
    const void* lin_w = d_in[12];
    const void* lin_b = d_in[13];

    char* ws = (char*)d_ws;
    size_t off = 0;
    auto alloc = [&](size_t bytes) { size_t o = off; off += (bytes + 255) & ~(size_t)255; return o; };

    // zeroed-at-start region (fast path needs only these three)
    size_t o_ncntA  = alloc(MP * 4);
    size_t o_pooled = alloc(256 * 4);
    size_t o_flags  = alloc(256);
    size_t zero_end = off;
    // general-path arrays (zeroed inside k_genprep when needed)
    size_t o_node_cnt   = alloc(MP * 4);
    size_t o_edge_cnt   = alloc(EP * 4);
    size_t o_node_delta = alloc(MP * 4);
    size_t o_edge_delta = alloc(EP * 4);
    size_t o_d0         = alloc(MP * 4);
    size_t o_d1         = alloc(EP * 4);
    size_t o_node_card = alloc(MP * 4);
    size_t o_edge_card = alloc(EP * 4);
    size_t o_node_ptr = alloc((size_t)(MP + 1) * 4);
    size_t o_edge_ptr = alloc((size_t)(EP + 1) * 4);
    size_t o_node_idx = alloc((size_t)NNZ_ * 4);
    size_t o_edge_idx = alloc((size_t)NNZ_ * 4);
    size_t o_smallf   = alloc(6 * 256 * 4);
    size_t o_pairN    = alloc((size_t)NNZ_ * 8);
    size_t o_pairE    = alloc((size_t)NNZ_ * 8);
    size_t o_Wt0_l0 = alloc(256 * 64 * 2);
    size_t o_Wt1_l0 = alloc(256 * 256 * 2);
    size_t o_Wt0_l1 = alloc(256 * 256 * 2);
    size_t o_Wt1_l1 = alloc(256 * 256 * 2);
    size_t o_E1 = alloc((size_t)EP * 256 * 2);
    size_t o_E2 = alloc((size_t)EP * 256 * 2);
    size_t o_N1 = alloc((size_t)MP * 256 * 2);
    if (off > ws_size) {
        k_sentinel<<<1, 1, 0, stream>>>(d_out);
        return;
    }

    int* ncntA = (int*)(ws + o_ncntA);
    float* pooled = (float*)(ws + o_pooled);
    int* flags = (int*)(ws + o_flags);
    int* node_cnt = (int*)(ws + o_node_cnt);
    int* edge_cnt = (int*)(ws + o_edge_cnt);
    float* node_delta = (float*)(ws + o_node_delta);
    float* edge_delta = (float*)(ws + o_edge_delta);
    float* d0 = (float*)(ws + o_d0);
    float* d1 = (float*)(ws + o_d1);
    float* node_card = (float*)(ws + o_node_card);
    float* edge_card = (float*)(ws + o_edge_card);
    int* node_ptr = (int*)(ws + o_node_ptr);
    int* edge_ptr = (int*)(ws + o_edge_ptr);
    int* node_idx = (int*)(ws + o_node_idx);
    int* edge_idx = (int*)(ws + o_edge_idx);
    float* smallf = (float*)(ws + o_smallf);
    int2* pairN = (int2*)(ws + o_pairN);
    int2* pairE = (int2*)(ws + o_pairE);
    ushort_t* Wt0_l0 = (ushort_t*)(ws + o_Wt0_l0);
    ushort_t* Wt1_l0 = (ushort_t*)(ws + o_Wt1_l0);
    ushort_t* Wt0_l1 = (ushort_t*)(ws + o_Wt0_l1);
    ushort_t* Wt1_l1 = (ushort_t*)(ws + o_Wt1_l1);
    ushort_t* E1 = (ushort_t*)(ws + o_E1);
    ushort_t* E2 = (ushort_t*)(ws + o_E2);
    ushort_t* N1 = (ushort_t*)(ws + o_N1);
    float* partial = (float*)(ws + o_E2);   // alias: E2 dead when partials written
    ushort_t* x0c = (ushort_t*)(ws + o_E2); // alias: f32->bf16 x0 staging

    const int NB = (NNZ_ + 255) / 256;        // 1563
    const int CVB = 3964;                     // conversion items / 256
    const int GB = (EP / 64) * 2;             // 1564 gemm blocks

    k_zero<<<128, 256, 0, stream>>>((uint_t*)ws, zero_end / 4);
    k_checkfill<<<NB, 256, 0, stream>>>(vals, rows, cols, ncntA, node_idx, flags);
    k_cvt_all<<<CVB, 256, 0, stream>>>(x0_in, W0_l0, W1_l0, W0_l1, W1_l1,
                                       b1_l0, b0_l0, b1_l1, b0_l1, lin_w, lin_b,
                                       x0c, Wt0_l0, Wt1_l0, Wt0_l1, Wt1_l1, smallf, flags);
    k_genprep<<<1, 1024, 0, stream>>>(vals, rows, cols, node_cnt, edge_cnt,
                                      node_delta, edge_delta, node_card, edge_card,
                                      d0, d1, node_ptr, edge_ptr, node_idx, edge_idx,
                                      pairN, pairE, flags);

    // ---- layer 0 ----  (aggregate-first: segsum((x W)[rows]*v) == segsum(x[rows]*v) @ W)
    k_aggEp<64><<<NBLK_E * 4, 256, 0, stream>>>((const ushort_t*)x0_in, x0c, rows,
                                                edge_ptr, pairE, E1, flags);
    k_gemm2<64><<<GB, 256, 0, stream>>>(E1, Wt0_l0, E2, smallf + 0 * 256, 1);
    k_gemm2<256><<<GB, 256, 0, stream>>>(E2, Wt1_l0, E1, nullptr, 0);
    k_aggNp<0><<<NBLK_N * 8, 256, 0, stream>>>(E1, node_idx, node_ptr, pairN,
                                               smallf + 1 * 256, N1, nullptr, flags);

    // ---- layer 1 ----
    k_aggEp<256><<<NBLK_E * 16, 256, 0, stream>>>(N1, N1, rows, edge_ptr, pairE,
                                                  E1, flags);
    k_gemm2<256><<<GB, 256, 0, stream>>>(E1, Wt0_l1, E2, smallf + 2 * 256, 1);
    k_gemm2<256><<<GB, 256, 0, stream>>>(E2, Wt1_l1, E1, nullptr, 0);
    k_aggNp<1><<<NBLK_N * 8, 256, 0, stream>>>(E1, node_idx, node_ptr, pairN,
                                               smallf + 3 * 256, nullptr, partial, flags);

    // ---- head ----
    k_pred<<<64, 256, 0, stream>>>(partial, pooled);
    k_final<<<1, 256, 0, stream>>>(pooled, smallf, d_out, flags);
}

// Round 10
// 339.117 us; speedup vs baseline: 1.3284x; 1.3284x over previous
//
#include <hip/hip_runtime.h>

#define N_NODES 100000
#define N_EDGES 50000
#define NNZ_    400000
#define MP 100032   // N_NODES padded to 64
#define EP 50048    // N_EDGES padded to 64

typedef unsigned short ushort_t;
typedef unsigned int uint_t;

typedef __attribute__((ext_vector_type(8))) short bf16x8;
typedef __attribute__((ext_vector_type(4))) float f32x4;

__device__ __forceinline__ float b2f(ushort_t u) {
    return __uint_as_float(((uint_t)u) << 16);
}
__device__ __forceinline__ ushort_t f2b(float f) {
    uint_t x = __float_as_uint(f);
    uint_t r = (x + 0x7fffu + ((x >> 16) & 1u)) >> 16;  // RNE
    return (ushort_t)r;
}
__device__ __forceinline__ float ldval(const void* p, int k, int bf) {
    return bf ? b2f(((const ushort_t*)p)[k]) : ((const float*)p)[k];
}
__device__ __forceinline__ float vb(bf16x8 v, int j) {
    return __uint_as_float(((uint_t)(ushort_t)v[j]) << 16);
}

__global__ void k_sentinel(void* out) { ((uint_t*)out)[0] = 0x44894489u; }

__global__ void k_zero(uint_t* p, size_t n) {
    size_t i = (size_t)blockIdx.x * 256 + threadIdx.x;
    size_t stride = (size_t)gridDim.x * 256;
    for (; i < n; i += stride) p[i] = 0u;
}

// flags[0]=dtype(1=bf16), flags[2]=edge-structure violation, flags[3]=node-deg!=4
__global__ void k_checkfill(const void* __restrict__ vals, const int* __restrict__ rows,
                            const int* __restrict__ cols, int* ncntA, int* nidx,
                            int* flags) {
    int k = blockIdx.x * 256 + threadIdx.x;
    int bf = (((const uint_t*)vals)[0] == 0x3F803F80u);
    if (k == 0 && blockIdx.x == 0) flags[0] = bf;
    if (k >= NNZ_) return;
    int bad = 0;
    if (cols[k] != (k >> 3)) bad = 1;
    if (bf) { if (((const ushort_t*)vals)[k] != 0x3F80) bad = 1; }
    else    { if (((const uint_t*)vals)[k] != 0x3F800000u) bad = 1; }
    if (bad) atomicOr(&flags[2], 1);
    int r = rows[k];
    if ((unsigned)r >= (unsigned)N_NODES) { atomicOr(&flags[3], 1); return; }
    int slot = atomicAdd(&ncntA[r], 1);
    if (slot < 4) nidx[r * 4 + slot] = (k >> 3);   // edge id directly
    else atomicOr(&flags[3], 1);
}

// conversions fused
__global__ void k_cvt_all(const void* x0, const void* W0l0, const void* W1l0,
                          const void* W0l1, const void* W1l1,
                          const void* b1l0, const void* b0l0, const void* b1l1,
                          const void* b0l1, const void* lw, const void* lb,
                          ushort_t* x0c, ushort_t* Wt0_l0, ushort_t* Wt1_l0,
                          ushort_t* Wt0_l1, ushort_t* Wt1_l1,
                          float* smallf, const int* __restrict__ flags) {
    int bf = flags[0];
    long i = (long)blockIdx.x * 256 + threadIdx.x;
    const long R0V = (long)N_NODES * 64 / 8;   // 800000 vector items
    if (i < R0V) {
        if (!bf) {
            const float* s = (const float*)x0 + i * 8;
            bf16x8 o;
#pragma unroll
            for (int j = 0; j < 8; ++j) o[j] = (short)f2b(s[j]);
            *(bf16x8*)(x0c + i * 8) = o;
        }
        return;
    }
    i -= R0V;
    if (i < 64 * 256) {
        int kk = i >> 8, n = i & 255;
        Wt0_l0[n * 64 + kk] = bf ? ((const ushort_t*)W0l0)[i] : f2b(((const float*)W0l0)[i]);
        return;
    }
    i -= 64 * 256;
    if (i < 65536) {
        int kk = i >> 8, n = i & 255;
        Wt1_l0[n * 256 + kk] = bf ? ((const ushort_t*)W1l0)[i] : f2b(((const float*)W1l0)[i]);
        return;
    }
    i -= 65536;
    if (i < 65536) {
        int kk = i >> 8, n = i & 255;
        Wt0_l1[n * 256 + kk] = bf ? ((const ushort_t*)W0l1)[i] : f2b(((const float*)W0l1)[i]);
        return;
    }
    i -= 65536;
    if (i < 65536) {
        int kk = i >> 8, n = i & 255;
        Wt1_l1[n * 256 + kk] = bf ? ((const ushort_t*)W1l1)[i] : f2b(((const float*)W1l1)[i]);
        return;
    }
    i -= 65536;
    if (i < 1536) {
        int b = i >> 8, t = i & 255;
        const void* srcs[6] = {b1l0, b0l0, b1l1, b0l1, lw, lb};
        int sz = (b == 5) ? 1 : 256;
        if (t < sz) smallf[b * 256 + t] = ldval(srcs[b], t, bf);
    }
}

// ---- general-path fallback: ONE single-block kernel (early-exits on fast path) ----
__global__ __launch_bounds__(1024) void k_genprep(
        const void* __restrict__ vals, const int* __restrict__ rows,
        const int* __restrict__ cols, int* ncnt, int* ecnt,
        float* ndelta, float* edelta, float* ncard, float* ecard,
        float* d0, float* d1, int* nptr, int* eptr, int* nidx, int* eidx,
        int2* pairN, int2* pairE, const int* __restrict__ flags) {
    if ((flags[2] | flags[3]) == 0) return;
    __shared__ int ss[1024];
    int t = threadIdx.x;
    int bf = flags[0];
    for (int i = t; i < MP; i += 1024) { ncnt[i] = 0; ndelta[i] = 0.f; d0[i] = 0.f; }
    for (int i = t; i < EP; i += 1024) { ecnt[i] = 0; edelta[i] = 0.f; d1[i] = 0.f; }
    __syncthreads();
    for (int k = t; k < NNZ_; k += 1024) {
        int r = rows[k], c = cols[k];
        if ((unsigned)r < (unsigned)N_NODES) atomicAdd(&ncnt[r], 1);
        if ((unsigned)c < (unsigned)N_EDGES) atomicAdd(&ecnt[c], 1);
        float v = ldval(vals, k, bf);
        if (v != 1.0f && (unsigned)r < (unsigned)N_NODES && (unsigned)c < (unsigned)N_EDGES) {
            atomicAdd(&ndelta[r], v - 1.f); atomicAdd(&edelta[c], v - 1.f);
        }
    }
    __syncthreads();
    for (int i = t; i < N_NODES; i += 1024) ncard[i] = rsqrtf((float)ncnt[i] + ndelta[i]);
    for (int i = t; i < N_EDGES; i += 1024) {
        float s = (float)ecnt[i] + edelta[i];
        ecard[i] = 1.f / (s * sqrtf(s));
    }
    __syncthreads();
    for (int k = t; k < NNZ_; k += 1024) {
        int r = rows[k], c = cols[k];
        if ((unsigned)r >= (unsigned)N_NODES || (unsigned)c >= (unsigned)N_EDGES) continue;
        float v = ldval(vals, k, bf);
        if (v != 0.f) {
            atomicAdd(&d0[r], ecard[c]); atomicAdd(&d1[c], ncard[r]);
        }
    }
    __syncthreads();
    {
        int chunk = (N_NODES + 1023) / 1024;
        int lo = t * chunk, hi = min(lo + chunk, N_NODES);
        int s = 0;
        for (int i = lo; i < hi; ++i) s += ncnt[i];
        ss[t] = s; __syncthreads();
        if (t == 0) {
            int acc = 0;
            for (int i = 0; i < 1024; ++i) { int x = ss[i]; ss[i] = acc; acc += x; }
            nptr[N_NODES] = acc;
        }
        __syncthreads();
        int acc = ss[t];
        for (int i = lo; i < hi; ++i) { nptr[i] = acc; acc += ncnt[i]; }
        __syncthreads();
        chunk = (N_EDGES + 1023) / 1024;
        lo = t * chunk; hi = min(lo + chunk, N_EDGES);
        s = 0;
        for (int i = lo; i < hi; ++i) s += ecnt[i];
        ss[t] = s; __syncthreads();
        if (t == 0) {
            int acc2 = 0;
            for (int i = 0; i < 1024; ++i) { int x = ss[i]; ss[i] = acc2; acc2 += x; }
            eptr[N_EDGES] = acc2;
        }
        __syncthreads();
        acc = ss[t];
        for (int i = lo; i < hi; ++i) { eptr[i] = acc; acc += ecnt[i]; }
        __syncthreads();
    }
    for (int i = t; i < N_NODES; i += 1024) ncnt[i] = 0;
    for (int i = t; i < N_EDGES; i += 1024) ecnt[i] = 0;
    __syncthreads();
    for (int k = t; k < NNZ_; k += 1024) {
        int r = rows[k], c = cols[k];
        if ((unsigned)r >= (unsigned)N_NODES || (unsigned)c >= (unsigned)N_EDGES) continue;
        nidx[nptr[r] + atomicAdd(&ncnt[r], 1)] = k;
        eidx[eptr[c] + atomicAdd(&ecnt[c], 1)] = k;
    }
    __syncthreads();
    int tot = nptr[N_NODES];
    for (int i = t; i < tot; i += 1024) {
        int k = nidx[i];
        int r = rows[k], c = cols[k];
        float wn = ldval(vals, k, bf) * ecard[c] / d0[r];
        pairN[i] = make_int2(c, __float_as_int(wn));
    }
    int tote = eptr[N_EDGES];
    for (int i = t; i < tote; i += 1024) {
        int ke = eidx[i];
        int rr = rows[ke];
        float wt = ldval(vals, ke, bf) * ncard[rr] / d1[cols[ke]];
        pairE[i] = make_int2(rr, __float_as_int(wt));
    }
}

// ---------------- GEMM: C[M,256] = A[M,K] @ W (Wt [256][K] transposed) ----------------
template <int K>
__global__ __launch_bounds__(256) void k_gemm2(const ushort_t* __restrict__ A,
                                               const ushort_t* __restrict__ Wt,
                                               ushort_t* __restrict__ C,
                                               const float* __restrict__ bias,
                                               int do_relu) {
    __shared__ ushort_t lds[32 * 512];   // 32 KB
    const int tid = threadIdx.x;
    const int lane = tid & 63;
    const int wave = tid >> 6;
    const int r16 = lane & 15;
    const int quad = lane >> 4;
    const int nh = blockIdx.x & 1;
    const int mblk = blockIdx.x >> 1;
    const int nbase = nh * 128;
    const int mbase = mblk * 64 + wave * 16;
    const ushort_t* Arow = A + (size_t)(mbase + r16) * K;

    f32x4 acc[8];
#pragma unroll
    for (int t = 0; t < 8; ++t) acc[t] = (f32x4){0.f, 0.f, 0.f, 0.f};

    constexpr int KCH = (K < 128) ? K : 128;
    constexpr int NF = (KCH / 32) * 8;
    for (int kc = 0; kc < K; kc += KCH) {
        __syncthreads();
        for (int f = wave; f < NF; f += 4) {
            int kb = f >> 3, t = f & 7;
            int n = nbase + t * 16 + r16;
            int kg = kc + kb * 32 + quad * 8;
            *(bf16x8*)(&lds[f * 512 + lane * 8]) = *(const bf16x8*)(Wt + (size_t)n * K + kg);
        }
        __syncthreads();
#pragma unroll
        for (int k0 = 0; k0 < KCH; k0 += 32) {
            bf16x8 af = *(const bf16x8*)(Arow + kc + k0 + quad * 8);
#pragma unroll
            for (int t = 0; t < 8; ++t) {
                bf16x8 bfr = *(const bf16x8*)(&lds[((k0 >> 5) * 8 + t) * 512 + lane * 8]);
                acc[t] = __builtin_amdgcn_mfma_f32_16x16x32_bf16(af, bfr, acc[t], 0, 0, 0);
            }
        }
    }
    const int mo = mbase + quad * 4;
#pragma unroll
    for (int t = 0; t < 8; ++t) {
        int n = nbase + t * 16 + r16;
        float b = bias ? bias[n] : 0.f;
#pragma unroll
        for (int r = 0; r < 4; ++r) {
            float v = acc[t][r] + b;
            if (do_relu) v = fmaxf(v, 0.f);
            C[(size_t)(mo + r) * 256 + n] = f2b(v);
        }
    }
}

// fast-path 8-row gather-average for one edge segment
template <int C>
__device__ __forceinline__ void gatherE8(const ushort_t* __restrict__ src,
                                         const int* __restrict__ rows,
                                         int seg, int ch, float* acc) {
    int4 a0 = *(const int4*)(rows + seg * 8);
    int4 a1 = *(const int4*)(rows + seg * 8 + 4);
    bf16x8 v0 = *(const bf16x8*)(src + (size_t)a0.x * C + ch);
    bf16x8 v1 = *(const bf16x8*)(src + (size_t)a0.y * C + ch);
    bf16x8 v2 = *(const bf16x8*)(src + (size_t)a0.z * C + ch);
    bf16x8 v3 = *(const bf16x8*)(src + (size_t)a0.w * C + ch);
    bf16x8 v4 = *(const bf16x8*)(src + (size_t)a1.x * C + ch);
    bf16x8 v5 = *(const bf16x8*)(src + (size_t)a1.y * C + ch);
    bf16x8 v6 = *(const bf16x8*)(src + (size_t)a1.z * C + ch);
    bf16x8 v7 = *(const bf16x8*)(src + (size_t)a1.w * C + ch);
#pragma unroll
    for (int j = 0; j < 8; ++j)
        acc[j] = 0.125f * (((vb(v0,j) + vb(v1,j)) + (vb(v2,j) + vb(v3,j))) +
                           ((vb(v4,j) + vb(v5,j)) + (vb(v6,j) + vb(v7,j))));
}

// ---- edge agg (full-row gathers, 2 segments/thread) ----
template <int C>
__global__ __launch_bounds__(256) void k_aggE(const ushort_t* __restrict__ srcA,
                                              const ushort_t* __restrict__ srcB,
                                              const int* __restrict__ rows,
                                              const int* __restrict__ eptr,
                                              const int2* __restrict__ pairE,
                                              ushort_t* __restrict__ dst,
                                              const int* __restrict__ flags) {
    constexpr int TPS = C / 8;
    constexpr int SPP = 256 / TPS;   // segments per pass
    const int sub = threadIdx.x / TPS;
    const int ch = (threadIdx.x % TPS) * 8;
    const int segA = blockIdx.x * (2 * SPP) + sub;
    const int segB = segA + SPP;
    const ushort_t* src = flags[0] ? srcA : srcB;
    const int fast = ((flags[2] | flags[3]) == 0);
    float accA[8], accB[8];
    const int vA = (segA < N_EDGES), vBv = (segB < N_EDGES);
    if (fast) {
        if (vA) gatherE8<C>(src, rows, segA, ch, accA);
        if (vBv) gatherE8<C>(src, rows, segB, ch, accB);
    } else {
        float* accs[2] = {accA, accB};
        int segs[2] = {segA, segB};
        int vs[2] = {vA, vBv};
        for (int p = 0; p < 2; ++p) {
            if (!vs[p]) continue;
            float* a = accs[p];
#pragma unroll
            for (int j = 0; j < 8; ++j) a[j] = 0.f;
            int lo = eptr[segs[p]], hi = eptr[segs[p] + 1];
            for (int i = lo; i < hi; ++i) {
                int2 pr = pairE[i];
                float w = __int_as_float(pr.y);
                bf16x8 v = *(const bf16x8*)(src + (size_t)pr.x * C + ch);
#pragma unroll
                for (int j = 0; j < 8; ++j) a[j] += w * vb(v, j);
            }
        }
    }
    if (vA) {
        bf16x8 o;
#pragma unroll
        for (int j = 0; j < 8; ++j) o[j] = (short)f2b(accA[j]);
        *(bf16x8*)(dst + (size_t)segA * C + ch) = o;
    }
    if (vBv) {
        bf16x8 o;
#pragma unroll
        for (int j = 0; j < 8; ++j) o[j] = (short)f2b(accB[j]);
        *(bf16x8*)(dst + (size_t)segB * C + ch) = o;
    }
}

// fast-path 4-row gather-average for one node segment
__device__ __forceinline__ void gatherN4(const ushort_t* __restrict__ src,
                                         const int* __restrict__ nidx,
                                         int seg, int ch, float* acc) {
    int4 i4 = *(const int4*)(nidx + seg * 4);
    bf16x8 v0 = *(const bf16x8*)(src + (size_t)i4.x * 256 + ch);
    bf16x8 v1 = *(const bf16x8*)(src + (size_t)i4.y * 256 + ch);
    bf16x8 v2 = *(const bf16x8*)(src + (size_t)i4.z * 256 + ch);
    bf16x8 v3 = *(const bf16x8*)(src + (size_t)i4.w * 256 + ch);
#pragma unroll
    for (int j = 0; j < 8; ++j)
        acc[j] = 0.25f * ((vb(v0,j) + vb(v1,j)) + (vb(v2,j) + vb(v3,j)));
}

// ---- node agg: 4 segments/thread (2x2), grid exact 3125x32=100000; POOL fuses max ----
template <int POOL>
__global__ __launch_bounds__(256) void k_aggN(const ushort_t* __restrict__ src,
                                              const int* __restrict__ nidx,
                                              const int* __restrict__ nptr,
                                              const int2* __restrict__ pairN,
                                              const float* __restrict__ bias,
                                              ushort_t* __restrict__ dst,
                                              float* __restrict__ partial,
                                              const int* __restrict__ flags) {
    __shared__ float sm[8][256];
    const int tid = threadIdx.x;
    const int sub = tid >> 5;            // 0..7
    const int ch = (tid & 31) * 8;
    const int base = blockIdx.x * 32 + sub;   // segs: base, base+8, base+16, base+24
    const int fast = ((flags[2] | flags[3]) == 0);
    float acc[4][8];
#pragma unroll
    for (int h = 0; h < 2; ++h) {        // two halves of 2 segments each
        int s0 = base + h * 16, s1 = s0 + 8;
        if (fast) {
            gatherN4(src, nidx, s0, ch, acc[h * 2 + 0]);
            gatherN4(src, nidx, s1, ch, acc[h * 2 + 1]);
        } else {
            for (int p = 0; p < 2; ++p) {
                float* a = acc[h * 2 + p];
#pragma unroll
                for (int j = 0; j < 8; ++j) a[j] = 0.f;
                int sg = (p == 0) ? s0 : s1;
                int lo = nptr[sg], hi = nptr[sg + 1];
                for (int i = lo; i < hi; ++i) {
                    int2 pr = pairN[i];
                    float w = __int_as_float(pr.y);
                    bf16x8 v = *(const bf16x8*)(src + (size_t)pr.x * 256 + ch);
#pragma unroll
                    for (int j = 0; j < 8; ++j) a[j] += w * vb(v, j);
                }
            }
        }
    }
    if (POOL) {
#pragma unroll
        for (int j = 0; j < 8; ++j) {
            float b = bias[ch + j];
            float m = fmaxf(fmaxf(acc[0][j] + b, 0.f), fmaxf(acc[1][j] + b, 0.f));
            m = fmaxf(m, fmaxf(fmaxf(acc[2][j] + b, 0.f), fmaxf(acc[3][j] + b, 0.f)));
            sm[sub][ch + j] = m;
        }
        __syncthreads();
        float mm = sm[0][tid];
#pragma unroll
        for (int g = 1; g < 8; ++g) mm = fmaxf(mm, sm[g][tid]);
        partial[(size_t)blockIdx.x * 256 + tid] = mm;
    } else {
#pragma unroll
        for (int q = 0; q < 4; ++q) {
            int sg = base + ((q >> 1) * 16) + ((q & 1) * 8);
            bf16x8 o;
#pragma unroll
            for (int j = 0; j < 8; ++j)
                o[j] = (short)f2b(fmaxf(acc[q][j] + bias[ch + j], 0.f));
            *(bf16x8*)(dst + (size_t)sg * 256 + ch) = o;
        }
    }
}

// ---------------- pool partial reduce + head ----------------
__global__ void k_pred(const float* __restrict__ partial, float* pooled) {
    int ch = threadIdx.x;
    float m = 0.f;   // post-ReLU >= 0
    for (int b = blockIdx.x; b < 3125; b += gridDim.x)
        m = fmaxf(m, partial[(size_t)b * 256 + ch]);
    atomicMax((int*)&pooled[ch], __float_as_int(m));
}

__global__ void k_final(const float* __restrict__ pooled, const float* __restrict__ smallf,
                        void* out, const int* __restrict__ flags) {
    __shared__ float red[256];
    int c = threadIdx.x;
    red[c] = pooled[c] * smallf[4 * 256 + c];   // lin_w
    __syncthreads();
    for (int s = 128; s > 0; s >>= 1) {
        if (c < s) red[c] += red[c + s];
        __syncthreads();
    }
    if (c == 0) {
        float r = red[0] + smallf[5 * 256 + 0]; // lin_b
        if (flags[0]) ((ushort_t*)out)[0] = f2b(r);
        else          ((float*)out)[0] = r;
    }
}

extern "C" void kernel_launch(void* const* d_in, const int* in_sizes, int n_in,
                              void* d_out, int out_size, void* d_ws, size_t ws_size,
                              hipStream_t stream) {
    const void* x0_in = d_in[0];
    const void* vals  = d_in[1];
    const int* rows = (const int*)d_in[2];
    const int* cols = (const int*)d_in[3];
    const void* W0_l0 = d_in[4];
    const void* W1_l0 = d_in[5];
    const void* b1_l0 = d_in[6];
    const void* b0_l0 = d_in[7];
    const void* W0_l1 = d_in[8];
    const void* W1_l1 = d_in[9];
    const void* b1_l1 = d_in[10];
    const void* b0_l1 = d_in[11];
    const void* lin_w = d_in[12];
    const void* lin_b = d_in[13];

    char* ws = (char*)d_ws;
    size_t off = 0;
    auto alloc = [&](size_t bytes) { size_t o = off; off += (bytes + 255) & ~(size_t)255; return o; };

    size_t o_ncntA  = alloc(MP * 4);
    size_t o_pooled = alloc(256 * 4);
    size_t o_flags  = alloc(256);
    size_t zero_end = off;
    size_t o_node_cnt   = alloc(MP * 4);
    size_t o_edge_cnt   = alloc(EP * 4);
    size_t o_node_delta = alloc(MP * 4);
    size_t o_edge_delta = alloc(EP * 4);
    size_t o_d0         = alloc(MP * 4);
    size_t o_d1         = alloc(EP * 4);
    size_t o_node_card = alloc(MP * 4);
    size_t o_edge_card = alloc(EP * 4);
    size_t o_node_ptr = alloc((size_t)(MP + 1) * 4);
    size_t o_edge_ptr = alloc((size_t)(EP + 1) * 4);
    size_t o_node_idx = alloc((size_t)NNZ_ * 4);
    size_t o_edge_idx = alloc((size_t)NNZ_ * 4);
    size_t o_smallf   = alloc(6 * 256 * 4);
    size_t o_pairN    = alloc((size_t)NNZ_ * 8);
    size_t o_pairE    = alloc((size_t)NNZ_ * 8);
    size_t o_Wt0_l0 = alloc(256 * 64 * 2);
    size_t o_Wt1_l0 = alloc(256 * 256 * 2);
    size_t o_Wt0_l1 = alloc(256 * 256 * 2);
    size_t o_Wt1_l1 = alloc(256 * 256 * 2);
    size_t o_E1 = alloc((size_t)EP * 256 * 2);
    size_t o_E2 = alloc((size_t)EP * 256 * 2);
    size_t o_N1 = alloc((size_t)MP * 256 * 2);
    if (off > ws_size) {
        k_sentinel<<<1, 1, 0, stream>>>(d_out);
        return;
    }

    int* ncntA = (int*)(ws + o_ncntA);
    float* pooled = (float*)(ws + o_pooled);
    int* flags = (int*)(ws + o_flags);
    int* node_cnt = (int*)(ws + o_node_cnt);
    int* edge_cnt = (int*)(ws + o_edge_cnt);
    float* node_delta = (float*)(ws + o_node_delta);
    float* edge_delta = (float*)(ws + o_edge_delta);
    float* d0 = (float*)(ws + o_d0);
    float* d1 = (float*)(ws + o_d1);
    float* node_card = (float*)(ws + o_node_card);
    float* edge_card = (float*)(ws + o_edge_card);
    int* node_ptr = (int*)(ws + o_node_ptr);
    int* edge_ptr = (int*)(ws + o_edge_ptr);
    int* node_idx = (int*)(ws + o_node_idx);
    int* edge_idx = (int*)(ws + o_edge_idx);
    float* smallf = (float*)(ws + o_smallf);
    int2* pairN = (int2*)(ws + o_pairN);
    int2* pairE = (int2*)(ws + o_pairE);
    ushort_t* Wt0_l0 = (ushort_t*)(ws + o_Wt0_l0);
    ushort_t* Wt1_l0 = (ushort_t*)(ws + o_Wt1_l0);
    ushort_t* Wt0_l1 = (ushort_t*)(ws + o_Wt0_l1);
    ushort_t* Wt1_l1 = (ushort_t*)(ws + o_Wt1_l1);
    ushort_t* E1 = (ushort_t*)(ws + o_E1);
    ushort_t* E2 = (ushort_t*)(ws + o_E2);
    ushort_t* N1 = (ushort_t*)(ws + o_N1);
    float* partial = (float*)(ws + o_E2);   // alias: E2 dead when partials written
    ushort_t* x0c = (ushort_t*)(ws + o_E2); // alias: f32->bf16 x0 staging

    const int NB = (NNZ_ + 255) / 256;        // 1563
    const int CVB = 3964;                     // conversion items / 256
    const int GB = (EP / 64) * 2;             // 1564 gemm blocks

    k_zero<<<128, 256, 0, stream>>>((uint_t*)ws, zero_end / 4);
    k_checkfill<<<NB, 256, 0, stream>>>(vals, rows, cols, ncntA, node_idx, flags);
    k_cvt_all<<<CVB, 256, 0, stream>>>(x0_in, W0_l0, W1_l0, W0_l1, W1_l1,
                                       b1_l0, b0_l0, b1_l1, b0_l1, lin_w, lin_b,
                                       x0c, Wt0_l0, Wt1_l0, Wt0_l1, Wt1_l1, smallf, flags);
    k_genprep<<<1, 1024, 0, stream>>>(vals, rows, cols, node_cnt, edge_cnt,
                                      node_delta, edge_delta, node_card, edge_card,
                                      d0, d1, node_ptr, edge_ptr, node_idx, edge_idx,
                                      pairN, pairE, flags);

    // ---- layer 0 ----  (aggregate-first: segsum((x W)[rows]*v) == segsum(x[rows]*v) @ W)
    k_aggE<64><<<(N_EDGES + 63) / 64, 256, 0, stream>>>((const ushort_t*)x0_in, x0c, rows,
                                                        edge_ptr, pairE, E1, flags);
    k_gemm2<64><<<GB, 256, 0, stream>>>(E1, Wt0_l0, E2, smallf + 0 * 256, 1);
    k_gemm2<256><<<GB, 256, 0, stream>>>(E2, Wt1_l0, E1, nullptr, 0);
    k_aggN<0><<<3125, 256, 0, stream>>>(E1, node_idx, node_ptr, pairN,
                                        smallf + 1 * 256, N1, nullptr, flags);

    // ---- layer 1 ----
    k_aggE<256><<<3125, 256, 0, stream>>>(N1, N1, rows, edge_ptr, pairE, E1, flags);
    k_gemm2<256><<<GB, 256, 0, stream>>>(E1, Wt0_l1, E2, smallf + 2 * 256, 1);
    k_gemm2<256><<<GB, 256, 0, stream>>>(E2, Wt1_l1, E1, nullptr, 0);
    k_aggN<1><<<3125, 256, 0, stream>>>(E1, node_idx, node_ptr, pairN,
                                        smallf + 3 * 256, nullptr, partial, flags);

    // ---- head ----
    k_pred<<<64, 256, 0, stream>>>(partial, pooled);
    k_final<<<1, 256, 0, stream>>>(pooled, smallf, d_out, flags);
}

// Round 11
// 336.999 us; speedup vs baseline: 1.3368x; 1.0063x over previous
//
#include <hip/hip_runtime.h>

#define N_NODES 100000
#define N_EDGES 50000
#define NNZ_    400000
#define MP 100032   // N_NODES padded to 64
#define EP 50048    // N_EDGES padded to 64

typedef unsigned short ushort_t;
typedef unsigned int uint_t;

typedef __attribute__((ext_vector_type(8))) short bf16x8;
typedef __attribute__((ext_vector_type(4))) float f32x4;

__device__ __forceinline__ float b2f(ushort_t u) {
    return __uint_as_float(((uint_t)u) << 16);
}
__device__ __forceinline__ ushort_t f2b(float f) {
    uint_t x = __float_as_uint(f);
    uint_t r = (x + 0x7fffu + ((x >> 16) & 1u)) >> 16;  // RNE
    return (ushort_t)r;
}
__device__ __forceinline__ float ldval(const void* p, int k, int bf) {
    return bf ? b2f(((const ushort_t*)p)[k]) : ((const float*)p)[k];
}
__device__ __forceinline__ float vb(bf16x8 v, int j) {
    return __uint_as_float(((uint_t)(ushort_t)v[j]) << 16);
}

__global__ void k_sentinel(void* out) { ((uint_t*)out)[0] = 0x44894489u; }

__global__ void k_zero(uint_t* p, size_t n) {
    size_t i = (size_t)blockIdx.x * 256 + threadIdx.x;
    size_t stride = (size_t)gridDim.x * 256;
    for (; i < n; i += stride) p[i] = 0u;
}

#define NB_CF 1563   // checkfill blocks
#define NB_CV 3964   // conversion blocks

// fused: [0,NB_CF) structure checks + fast node-CSR fill; [NB_CF,..) conversions
// flags[0]=dtype(1=bf16), flags[2]=edge-structure violation, flags[3]=node-deg!=4
__global__ void k_prep(const void* __restrict__ vals, const int* __restrict__ rows,
                       const int* __restrict__ cols, int* ncntA, int* nidx, int* flags,
                       const void* x0, const void* W0l0, const void* W1l0,
                       const void* W0l1, const void* W1l1,
                       const void* b1l0, const void* b0l0, const void* b1l1,
                       const void* b0l1, const void* lw, const void* lb,
                       ushort_t* x0c, ushort_t* Wt0_l0, ushort_t* Wt1_l0,
                       ushort_t* Wt0_l1, ushort_t* Wt1_l1, float* smallf) {
    int bf = (((const uint_t*)vals)[0] == 0x3F803F80u);
    if (blockIdx.x < NB_CF) {
        int k = blockIdx.x * 256 + threadIdx.x;
        if (k == 0) flags[0] = bf;
        if (k >= NNZ_) return;
        int bad = 0;
        if (cols[k] != (k >> 3)) bad = 1;
        if (bf) { if (((const ushort_t*)vals)[k] != 0x3F80) bad = 1; }
        else    { if (((const uint_t*)vals)[k] != 0x3F800000u) bad = 1; }
        if (bad) atomicOr(&flags[2], 1);
        int r = rows[k];
        if ((unsigned)r >= (unsigned)N_NODES) { atomicOr(&flags[3], 1); return; }
        int slot = atomicAdd(&ncntA[r], 1);
        if (slot < 4) nidx[r * 4 + slot] = (k >> 3);   // edge id directly
        else atomicOr(&flags[3], 1);
        return;
    }
    long i = (long)(blockIdx.x - NB_CF) * 256 + threadIdx.x;
    const long R0V = (long)N_NODES * 64 / 8;   // 800000 vector items
    if (i < R0V) {
        if (!bf) {   // bf16 x0 used in place; only f32 needs conversion
            const float* s = (const float*)x0 + i * 8;
            bf16x8 o;
#pragma unroll
            for (int j = 0; j < 8; ++j) o[j] = (short)f2b(s[j]);
            *(bf16x8*)(x0c + i * 8) = o;
        }
        return;
    }
    i -= R0V;
    if (i < 64 * 256) {
        int kk = i >> 8, n = i & 255;
        Wt0_l0[n * 64 + kk] = bf ? ((const ushort_t*)W0l0)[i] : f2b(((const float*)W0l0)[i]);
        return;
    }
    i -= 64 * 256;
    if (i < 65536) {
        int kk = i >> 8, n = i & 255;
        Wt1_l0[n * 256 + kk] = bf ? ((const ushort_t*)W1l0)[i] : f2b(((const float*)W1l0)[i]);
        return;
    }
    i -= 65536;
    if (i < 65536) {
        int kk = i >> 8, n = i & 255;
        Wt0_l1[n * 256 + kk] = bf ? ((const ushort_t*)W0l1)[i] : f2b(((const float*)W0l1)[i]);
        return;
    }
    i -= 65536;
    if (i < 65536) {
        int kk = i >> 8, n = i & 255;
        Wt1_l1[n * 256 + kk] = bf ? ((const ushort_t*)W1l1)[i] : f2b(((const float*)W1l1)[i]);
        return;
    }
    i -= 65536;
    if (i < 1536) {
        int b = i >> 8, t = i & 255;
        const void* srcs[6] = {b1l0, b0l0, b1l1, b0l1, lw, lb};
        int sz = (b == 5) ? 1 : 256;
        if (t < sz) smallf[b * 256 + t] = ldval(srcs[b], t, bf);
    }
}

// ---- general-path fallback: ONE single-block kernel (early-exits on fast path) ----
__global__ __launch_bounds__(1024) void k_genprep(
        const void* __restrict__ vals, const int* __restrict__ rows,
        const int* __restrict__ cols, int* ncnt, int* ecnt,
        float* ndelta, float* edelta, float* ncard, float* ecard,
        float* d0, float* d1, int* nptr, int* eptr, int* nidx, int* eidx,
        int2* pairN, int2* pairE, const int* __restrict__ flags) {
    if ((flags[2] | flags[3]) == 0) return;
    __shared__ int ss[1024];
    int t = threadIdx.x;
    int bf = flags[0];
    for (int i = t; i < MP; i += 1024) { ncnt[i] = 0; ndelta[i] = 0.f; d0[i] = 0.f; }
    for (int i = t; i < EP; i += 1024) { ecnt[i] = 0; edelta[i] = 0.f; d1[i] = 0.f; }
    __syncthreads();
    for (int k = t; k < NNZ_; k += 1024) {
        int r = rows[k], c = cols[k];
        if ((unsigned)r < (unsigned)N_NODES) atomicAdd(&ncnt[r], 1);
        if ((unsigned)c < (unsigned)N_EDGES) atomicAdd(&ecnt[c], 1);
        float v = ldval(vals, k, bf);
        if (v != 1.0f && (unsigned)r < (unsigned)N_NODES && (unsigned)c < (unsigned)N_EDGES) {
            atomicAdd(&ndelta[r], v - 1.f); atomicAdd(&edelta[c], v - 1.f);
        }
    }
    __syncthreads();
    for (int i = t; i < N_NODES; i += 1024) ncard[i] = rsqrtf((float)ncnt[i] + ndelta[i]);
    for (int i = t; i < N_EDGES; i += 1024) {
        float s = (float)ecnt[i] + edelta[i];
        ecard[i] = 1.f / (s * sqrtf(s));
    }
    __syncthreads();
    for (int k = t; k < NNZ_; k += 1024) {
        int r = rows[k], c = cols[k];
        if ((unsigned)r >= (unsigned)N_NODES || (unsigned)c >= (unsigned)N_EDGES) continue;
        float v = ldval(vals, k, bf);
        if (v != 0.f) {
            atomicAdd(&d0[r], ecard[c]); atomicAdd(&d1[c], ncard[r]);
        }
    }
    __syncthreads();
    {
        int chunk = (N_NODES + 1023) / 1024;
        int lo = t * chunk, hi = min(lo + chunk, N_NODES);
        int s = 0;
        for (int i = lo; i < hi; ++i) s += ncnt[i];
        ss[t] = s; __syncthreads();
        if (t == 0) {
            int acc = 0;
            for (int i = 0; i < 1024; ++i) { int x = ss[i]; ss[i] = acc; acc += x; }
            nptr[N_NODES] = acc;
        }
        __syncthreads();
        int acc = ss[t];
        for (int i = lo; i < hi; ++i) { nptr[i] = acc; acc += ncnt[i]; }
        __syncthreads();
        chunk = (N_EDGES + 1023) / 1024;
        lo = t * chunk; hi = min(lo + chunk, N_EDGES);
        s = 0;
        for (int i = lo; i < hi; ++i) s += ecnt[i];
        ss[t] = s; __syncthreads();
        if (t == 0) {
            int acc2 = 0;
            for (int i = 0; i < 1024; ++i) { int x = ss[i]; ss[i] = acc2; acc2 += x; }
            eptr[N_EDGES] = acc2;
        }
        __syncthreads();
        acc = ss[t];
        for (int i = lo; i < hi; ++i) { eptr[i] = acc; acc += ecnt[i]; }
        __syncthreads();
    }
    for (int i = t; i < N_NODES; i += 1024) ncnt[i] = 0;
    for (int i = t; i < N_EDGES; i += 1024) ecnt[i] = 0;
    __syncthreads();
    for (int k = t; k < NNZ_; k += 1024) {
        int r = rows[k], c = cols[k];
        if ((unsigned)r >= (unsigned)N_NODES || (unsigned)c >= (unsigned)N_EDGES) continue;
        nidx[nptr[r] + atomicAdd(&ncnt[r], 1)] = k;
        eidx[eptr[c] + atomicAdd(&ecnt[c], 1)] = k;
    }
    __syncthreads();
    int tot = nptr[N_NODES];
    for (int i = t; i < tot; i += 1024) {
        int k = nidx[i];
        int r = rows[k], c = cols[k];
        float wn = ldval(vals, k, bf) * ecard[c] / d0[r];
        pairN[i] = make_int2(c, __float_as_int(wn));
    }
    int tote = eptr[N_EDGES];
    for (int i = t; i < tote; i += 1024) {
        int ke = eidx[i];
        int rr = rows[ke];
        float wt = ldval(vals, ke, bf) * ncard[rr] / d1[cols[ke]];
        pairE[i] = make_int2(rr, __float_as_int(wt));
    }
}

// ---------------- GEMM: C[M,256] = A[M,K] @ W (Wt [256][K] transposed) ----------------
template <int K>
__global__ __launch_bounds__(256) void k_gemm2(const ushort_t* __restrict__ A,
                                               const ushort_t* __restrict__ Wt,
                                               ushort_t* __restrict__ C,
                                               const float* __restrict__ bias,
                                               int do_relu) {
    __shared__ ushort_t lds[32 * 512];   // 32 KB
    const int tid = threadIdx.x;
    const int lane = tid & 63;
    const int wave = tid >> 6;
    const int r16 = lane & 15;
    const int quad = lane >> 4;
    const int nh = blockIdx.x & 1;
    const int mblk = blockIdx.x >> 1;
    const int nbase = nh * 128;
    const int mbase = mblk * 64 + wave * 16;
    const ushort_t* Arow = A + (size_t)(mbase + r16) * K;

    f32x4 acc[8];
#pragma unroll
    for (int t = 0; t < 8; ++t) acc[t] = (f32x4){0.f, 0.f, 0.f, 0.f};

    constexpr int KCH = (K < 128) ? K : 128;
    constexpr int NF = (KCH / 32) * 8;
    for (int kc = 0; kc < K; kc += KCH) {
        __syncthreads();
        for (int f = wave; f < NF; f += 4) {
            int kb = f >> 3, t = f & 7;
            int n = nbase + t * 16 + r16;
            int kg = kc + kb * 32 + quad * 8;
            *(bf16x8*)(&lds[f * 512 + lane * 8]) = *(const bf16x8*)(Wt + (size_t)n * K + kg);
        }
        __syncthreads();
#pragma unroll
        for (int k0 = 0; k0 < KCH; k0 += 32) {
            bf16x8 af = *(const bf16x8*)(Arow + kc + k0 + quad * 8);
#pragma unroll
            for (int t = 0; t < 8; ++t) {
                bf16x8 bfr = *(const bf16x8*)(&lds[((k0 >> 5) * 8 + t) * 512 + lane * 8]);
                acc[t] = __builtin_amdgcn_mfma_f32_16x16x32_bf16(af, bfr, acc[t], 0, 0, 0);
            }
        }
    }
    const int mo = mbase + quad * 4;
#pragma unroll
    for (int t = 0; t < 8; ++t) {
        int n = nbase + t * 16 + r16;
        float b = bias ? bias[n] : 0.f;
#pragma unroll
        for (int r = 0; r < 4; ++r) {
            float v = acc[t][r] + b;
            if (do_relu) v = fmaxf(v, 0.f);
            C[(size_t)(mo + r) * 256 + n] = f2b(v);
        }
    }
}

// ---- edge agg: 2 segments/thread, ALL 16 gathers issued before any reduce ----
template <int C>
__global__ __launch_bounds__(256) void k_aggE(const ushort_t* __restrict__ srcA,
                                              const ushort_t* __restrict__ srcB,
                                              const int* __restrict__ rows,
                                              const int* __restrict__ eptr,
                                              const int2* __restrict__ pairE,
                                              ushort_t* __restrict__ dst,
                                              const int* __restrict__ flags) {
    constexpr int TPS = C / 8;
    constexpr int SPP = 256 / TPS;   // segments per pass
    const int sub = threadIdx.x / TPS;
    const int ch = (threadIdx.x % TPS) * 8;
    const int segA = blockIdx.x * (2 * SPP) + sub;
    const int segB = segA + SPP;
    const ushort_t* src = flags[0] ? srcA : srcB;
    const int fast = ((flags[2] | flags[3]) == 0);
    const int vA = (segA < N_EDGES), vBv = (segB < N_EDGES);
    float accA[8], accB[8];
    if (fast) {
        int4 a0, a1, b0, b1;
        if (vA) { a0 = *(const int4*)(rows + segA * 8); a1 = *(const int4*)(rows + segA * 8 + 4); }
        if (vBv) { b0 = *(const int4*)(rows + segB * 8); b1 = *(const int4*)(rows + segB * 8 + 4); }
        bf16x8 u[16];
        if (vA) {   // 8 independent loads, no intervening uses
            u[0] = *(const bf16x8*)(src + (size_t)a0.x * C + ch);
            u[1] = *(const bf16x8*)(src + (size_t)a0.y * C + ch);
            u[2] = *(const bf16x8*)(src + (size_t)a0.z * C + ch);
            u[3] = *(const bf16x8*)(src + (size_t)a0.w * C + ch);
            u[4] = *(const bf16x8*)(src + (size_t)a1.x * C + ch);
            u[5] = *(const bf16x8*)(src + (size_t)a1.y * C + ch);
            u[6] = *(const bf16x8*)(src + (size_t)a1.z * C + ch);
            u[7] = *(const bf16x8*)(src + (size_t)a1.w * C + ch);
        }
        if (vBv) {
            u[8]  = *(const bf16x8*)(src + (size_t)b0.x * C + ch);
            u[9]  = *(const bf16x8*)(src + (size_t)b0.y * C + ch);
            u[10] = *(const bf16x8*)(src + (size_t)b0.z * C + ch);
            u[11] = *(const bf16x8*)(src + (size_t)b0.w * C + ch);
            u[12] = *(const bf16x8*)(src + (size_t)b1.x * C + ch);
            u[13] = *(const bf16x8*)(src + (size_t)b1.y * C + ch);
            u[14] = *(const bf16x8*)(src + (size_t)b1.z * C + ch);
            u[15] = *(const bf16x8*)(src + (size_t)b1.w * C + ch);
        }
#pragma unroll
        for (int j = 0; j < 8; ++j) {
            accA[j] = 0.125f * (((vb(u[0],j) + vb(u[1],j)) + (vb(u[2],j) + vb(u[3],j))) +
                                ((vb(u[4],j) + vb(u[5],j)) + (vb(u[6],j) + vb(u[7],j))));
            accB[j] = 0.125f * (((vb(u[8],j) + vb(u[9],j)) + (vb(u[10],j) + vb(u[11],j))) +
                                ((vb(u[12],j) + vb(u[13],j)) + (vb(u[14],j) + vb(u[15],j))));
        }
    } else {
        float* accs[2] = {accA, accB};
        int segs[2] = {segA, segB};
        int vs[2] = {vA, vBv};
        for (int p = 0; p < 2; ++p) {
            if (!vs[p]) continue;
            float* a = accs[p];
#pragma unroll
            for (int j = 0; j < 8; ++j) a[j] = 0.f;
            int lo = eptr[segs[p]], hi = eptr[segs[p] + 1];
            for (int i = lo; i < hi; ++i) {
                int2 pr = pairE[i];
                float w = __int_as_float(pr.y);
                bf16x8 v = *(const bf16x8*)(src + (size_t)pr.x * C + ch);
#pragma unroll
                for (int j = 0; j < 8; ++j) a[j] += w * vb(v, j);
            }
        }
    }
    if (vA) {
        bf16x8 o;
#pragma unroll
        for (int j = 0; j < 8; ++j) o[j] = (short)f2b(accA[j]);
        *(bf16x8*)(dst + (size_t)segA * C + ch) = o;
    }
    if (vBv) {
        bf16x8 o;
#pragma unroll
        for (int j = 0; j < 8; ++j) o[j] = (short)f2b(accB[j]);
        *(bf16x8*)(dst + (size_t)segB * C + ch) = o;
    }
}

// ---- node agg: 4 segments/thread, ALL 16 gathers issued before any reduce ----
// grid exact 3125x32=100000; POOL fuses max-pool
template <int POOL>
__global__ __launch_bounds__(256) void k_aggN(const ushort_t* __restrict__ src,
                                              const int* __restrict__ nidx,
                                              const int* __restrict__ nptr,
                                              const int2* __restrict__ pairN,
                                              const float* __restrict__ bias,
                                              ushort_t* __restrict__ dst,
                                              float* __restrict__ partial,
                                              const int* __restrict__ flags) {
    __shared__ float sm[8][256];
    const int tid = threadIdx.x;
    const int sub = tid >> 5;            // 0..7
    const int ch = (tid & 31) * 8;
    const int base = blockIdx.x * 32 + sub;   // segs: base, base+8, base+16, base+24
    const int fast = ((flags[2] | flags[3]) == 0);
    float acc[4][8];
    if (fast) {
        int4 i0 = *(const int4*)(nidx + (size_t)(base +  0) * 4);
        int4 i1 = *(const int4*)(nidx + (size_t)(base +  8) * 4);
        int4 i2 = *(const int4*)(nidx + (size_t)(base + 16) * 4);
        int4 i3 = *(const int4*)(nidx + (size_t)(base + 24) * 4);
        bf16x8 u[16];
        u[0]  = *(const bf16x8*)(src + (size_t)i0.x * 256 + ch);
        u[1]  = *(const bf16x8*)(src + (size_t)i0.y * 256 + ch);
        u[2]  = *(const bf16x8*)(src + (size_t)i0.z * 256 + ch);
        u[3]  = *(const bf16x8*)(src + (size_t)i0.w * 256 + ch);
        u[4]  = *(const bf16x8*)(src + (size_t)i1.x * 256 + ch);
        u[5]  = *(const bf16x8*)(src + (size_t)i1.y * 256 + ch);
        u[6]  = *(const bf16x8*)(src + (size_t)i1.z * 256 + ch);
        u[7]  = *(const bf16x8*)(src + (size_t)i1.w * 256 + ch);
        u[8]  = *(const bf16x8*)(src + (size_t)i2.x * 256 + ch);
        u[9]  = *(const bf16x8*)(src + (size_t)i2.y * 256 + ch);
        u[10] = *(const bf16x8*)(src + (size_t)i2.z * 256 + ch);
        u[11] = *(const bf16x8*)(src + (size_t)i2.w * 256 + ch);
        u[12] = *(const bf16x8*)(src + (size_t)i3.x * 256 + ch);
        u[13] = *(const bf16x8*)(src + (size_t)i3.y * 256 + ch);
        u[14] = *(const bf16x8*)(src + (size_t)i3.z * 256 + ch);
        u[15] = *(const bf16x8*)(src + (size_t)i3.w * 256 + ch);
#pragma unroll
        for (int q = 0; q < 4; ++q)
#pragma unroll
            for (int j = 0; j < 8; ++j)
                acc[q][j] = 0.25f * ((vb(u[q*4+0],j) + vb(u[q*4+1],j)) +
                                     (vb(u[q*4+2],j) + vb(u[q*4+3],j)));
    } else {
        for (int p = 0; p < 4; ++p) {
            float* a = acc[p];
#pragma unroll
            for (int j = 0; j < 8; ++j) a[j] = 0.f;
            int sg = base + p * 8;
            int lo = nptr[sg], hi = nptr[sg + 1];
            for (int i = lo; i < hi; ++i) {
                int2 pr = pairN[i];
                float w = __int_as_float(pr.y);
                bf16x8 v = *(const bf16x8*)(src + (size_t)pr.x * 256 + ch);
#pragma unroll
                for (int j = 0; j < 8; ++j) a[j] += w * vb(v, j);
            }
        }
    }
    if (POOL) {
#pragma unroll
        for (int j = 0; j < 8; ++j) {
            float b = bias[ch + j];
            float m = fmaxf(fmaxf(acc[0][j] + b, 0.f), fmaxf(acc[1][j] + b, 0.f));
            m = fmaxf(m, fmaxf(fmaxf(acc[2][j] + b, 0.f), fmaxf(acc[3][j] + b, 0.f)));
            sm[sub][ch + j] = m;
        }
        __syncthreads();
        float mm = sm[0][tid];
#pragma unroll
        for (int g = 1; g < 8; ++g) mm = fmaxf(mm, sm[g][tid]);
        partial[(size_t)blockIdx.x * 256 + tid] = mm;
    } else {
#pragma unroll
        for (int q = 0; q < 4; ++q) {
            int sg = base + q * 8;
            bf16x8 o;
#pragma unroll
            for (int j = 0; j < 8; ++j)
                o[j] = (short)f2b(fmaxf(acc[q][j] + bias[ch + j], 0.f));
            *(bf16x8*)(dst + (size_t)sg * 256 + ch) = o;
        }
    }
}

// ---------------- pool partial reduce + head ----------------
__global__ void k_pred(const float* __restrict__ partial, float* pooled) {
    int ch = threadIdx.x;
    float m = 0.f;   // post-ReLU >= 0
    for (int b = blockIdx.x; b < 3125; b += gridDim.x)
        m = fmaxf(m, partial[(size_t)b * 256 + ch]);
    atomicMax((int*)&pooled[ch], __float_as_int(m));
}

__global__ void k_final(const float* __restrict__ pooled, const float* __restrict__ smallf,
                        void* out, const int* __restrict__ flags) {
    __shared__ float red[256];
    int c = threadIdx.x;
    red[c] = pooled[c] * smallf[4 * 256 + c];   // lin_w
    __syncthreads();
    for (int s = 128; s > 0; s >>= 1) {
        if (c < s) red[c] += red[c + s];
        __syncthreads();
    }
    if (c == 0) {
        float r = red[0] + smallf[5 * 256 + 0]; // lin_b
        if (flags[0]) ((ushort_t*)out)[0] = f2b(r);
        else          ((float*)out)[0] = r;
    }
}

extern "C" void kernel_launch(void* const* d_in, const int* in_sizes, int n_in,
                              void* d_out, int out_size, void* d_ws, size_t ws_size,
                              hipStream_t stream) {
    const void* x0_in = d_in[0];
    const void* vals  = d_in[1];
    const int* rows = (const int*)d_in[2];
    const int* cols = (const int*)d_in[3];
    const void* W0_l0 = d_in[4];
    const void* W1_l0 = d_in[5];
    const void* b1_l0 = d_in[6];
    const void* b0_l0 = d_in[7];
    const void* W0_l1 = d_in[8];
    const void* W1_l1 = d_in[9];
    const void* b1_l1 = d_in[10];
    const void* b0_l1 = d_in[11];
    const void* lin_w = d_in[12];
    const void* lin_b = d_in[13];

    char* ws = (char*)d_ws;
    size_t off = 0;
    auto alloc = [&](size_t bytes) { size_t o = off; off += (bytes + 255) & ~(size_t)255; return o; };

    size_t o_ncntA  = alloc(MP * 4);
    size_t o_pooled = alloc(256 * 4);
    size_t o_flags  = alloc(256);
    size_t zero_end = off;
    size_t o_node_cnt   = alloc(MP * 4);
    size_t o_edge_cnt   = alloc(EP * 4);
    size_t o_node_delta = alloc(MP * 4);
    size_t o_edge_delta = alloc(EP * 4);
    size_t o_d0         = alloc(MP * 4);
    size_t o_d1         = alloc(EP * 4);
    size_t o_node_card = alloc(MP * 4);
    size_t o_edge_card = alloc(EP * 4);
    size_t o_node_ptr = alloc((size_t)(MP + 1) * 4);
    size_t o_edge_ptr = alloc((size_t)(EP + 1) * 4);
    size_t o_node_idx = alloc((size_t)NNZ_ * 4);
    size_t o_edge_idx = alloc((size_t)NNZ_ * 4);
    size_t o_smallf   = alloc(6 * 256 * 4);
    size_t o_pairN    = alloc((size_t)NNZ_ * 8);
    size_t o_pairE    = alloc((size_t)NNZ_ * 8);
    size_t o_Wt0_l0 = alloc(256 * 64 * 2);
    size_t o_Wt1_l0 = alloc(256 * 256 * 2);
    size_t o_Wt0_l1 = alloc(256 * 256 * 2);
    size_t o_Wt1_l1 = alloc(256 * 256 * 2);
    size_t o_E1 = alloc((size_t)EP * 256 * 2);
    size_t o_E2 = alloc((size_t)EP * 256 * 2);
    size_t o_N1 = alloc((size_t)MP * 256 * 2);
    if (off > ws_size) {
        k_sentinel<<<1, 1, 0, stream>>>(d_out);
        return;
    }

    int* ncntA = (int*)(ws + o_ncntA);
    float* pooled = (float*)(ws + o_pooled);
    int* flags = (int*)(ws + o_flags);
    int* node_cnt = (int*)(ws + o_node_cnt);
    int* edge_cnt = (int*)(ws + o_edge_cnt);
    float* node_delta = (float*)(ws + o_node_delta);
    float* edge_delta = (float*)(ws + o_edge_delta);
    float* d0 = (float*)(ws + o_d0);
    float* d1 = (float*)(ws + o_d1);
    float* node_card = (float*)(ws + o_node_card);
    float* edge_card = (float*)(ws + o_edge_card);
    int* node_ptr = (int*)(ws + o_node_ptr);
    int* edge_ptr = (int*)(ws + o_edge_ptr);
    int* node_idx = (int*)(ws + o_node_idx);
    int* edge_idx = (int*)(ws + o_edge_idx);
    float* smallf = (float*)(ws + o_smallf);
    int2* pairN = (int2*)(ws + o_pairN);
    int2* pairE = (int2*)(ws + o_pairE);
    ushort_t* Wt0_l0 = (ushort_t*)(ws + o_Wt0_l0);
    ushort_t* Wt1_l0 = (ushort_t*)(ws + o_Wt1_l0);
    ushort_t* Wt0_l1 = (ushort_t*)(ws + o_Wt0_l1);
    ushort_t* Wt1_l1 = (ushort_t*)(ws + o_Wt1_l1);
    ushort_t* E1 = (ushort_t*)(ws + o_E1);
    ushort_t* E2 = (ushort_t*)(ws + o_E2);
    ushort_t* N1 = (ushort_t*)(ws + o_N1);
    float* partial = (float*)(ws + o_E2);   // alias: E2 dead when partials written
    ushort_t* x0c = (ushort_t*)(ws + o_E2); // alias: f32->bf16 x0 staging

    const int GB = (EP / 64) * 2;             // 1564 gemm blocks

    k_zero<<<128, 256, 0, stream>>>((uint_t*)ws, zero_end / 4);
    k_prep<<<NB_CF + NB_CV, 256, 0, stream>>>(vals, rows, cols, ncntA, node_idx, flags,
                                              x0_in, W0_l0, W1_l0, W0_l1, W1_l1,
                                              b1_l0, b0_l0, b1_l1, b0_l1, lin_w, lin_b,
                                              x0c, Wt0_l0, Wt1_l0, Wt0_l1, Wt1_l1, smallf);
    k_genprep<<<1, 1024, 0, stream>>>(vals, rows, cols, node_cnt, edge_cnt,
                                      node_delta, edge_delta, node_card, edge_card,
                                      d0, d1, node_ptr, edge_ptr, node_idx, edge_idx,
                                      pairN, pairE, flags);

    // ---- layer 0 ----  (aggregate-first: segsum((x W)[rows]*v) == segsum(x[rows]*v) @ W)
    k_aggE<64><<<(N_EDGES + 63) / 64, 256, 0, stream>>>((const ushort_t*)x0_in, x0c, rows,
                                                        edge_ptr, pairE, E1, flags);
    k_gemm2<64><<<GB, 256, 0, stream>>>(E1, Wt0_l0, E2, smallf + 0 * 256, 1);
    k_gemm2<256><<<GB, 256, 0, stream>>>(E2, Wt1_l0, E1, nullptr, 0);
    k_aggN<0><<<3125, 256, 0, stream>>>(E1, node_idx, node_ptr, pairN,
                                        smallf + 1 * 256, N1, nullptr, flags);

    // ---- layer 1 ----
    k_aggE<256><<<3125, 256, 0, stream>>>(N1, N1, rows, edge_ptr, pairE, E1, flags);
    k_gemm2<256><<<GB, 256, 0, stream>>>(E1, Wt0_l1, E2, smallf + 2 * 256, 1);
    k_gemm2<256><<<GB, 256, 0, stream>>>(E2, Wt1_l1, E1, nullptr, 0);
    k_aggN<1><<<3125, 256, 0, stream>>>(E1, node_idx, node_ptr, pairN,
                                        smallf + 3 * 256, nullptr, partial, flags);

    // ---- head ----
    k_pred<<<64, 256, 0, stream>>>(partial, pooled);
    k_final<<<1, 256, 0, stream>>>(pooled, smallf, d_out, flags);
}